// Round 1
// baseline (153.420 us; speedup 1.0000x reference)
//
#include <hip/hip_runtime.h>
#include <stdint.h>

#define N_ROWS 4096
#define DIM    1024
#define NCLS   64
#define EPSV   0.1f

typedef __attribute__((ext_vector_type(8))) __bf16 bf16x8;
typedef __attribute__((ext_vector_type(4))) float  f32x4;

__device__ __forceinline__ unsigned short f2bf(float f) {
    union { float f; unsigned u; } v; v.f = f;
    unsigned r = v.u + 0x7FFF + ((v.u >> 16) & 1);   // RNE
    return (unsigned short)(r >> 16);
}

__device__ __forceinline__ void async_cp16(const void* g, void* l) {
    __builtin_amdgcn_global_load_lds((const __attribute__((address_space(1))) void*)g,
                                     (__attribute__((address_space(3))) void*)l,
                                     16, 0, 0);
}

__device__ __forceinline__ float softplus(float x) {
    return fmaxf(x, 0.f) + __logf(1.f + __expf(-fabsf(x)));
}

// ---------------- K1: class counts + pair-count scalars + zero loss ----------
__global__ __launch_bounds__(256) void k_counts(const int* __restrict__ tgt,
                                                int* __restrict__ counts_out,
                                                float* __restrict__ scal,
                                                float* __restrict__ loss_out) {
    __shared__ int cnt[NCLS];
    int tid = threadIdx.x;
    if (tid < NCLS) cnt[tid] = 0;
    __syncthreads();
    for (int i = tid; i < N_ROWS; i += 256) atomicAdd(&cnt[tgt[i]], 1);
    __syncthreads();
    if (tid < NCLS) counts_out[tid] = cnt[tid];
    if (tid == 0) {
        long long sp = 0, ss = 0;
        for (int c = 0; c < NCLS; c++) { long long cc = cnt[c]; sp += cc * (cc - 1); ss += cc * cc; }
        scal[0] = (float)sp;                                       // cnt_pos
        scal[1] = (float)((long long)N_ROWS * N_ROWS - ss);        // cnt_neg
        loss_out[0] = 0.0f;
    }
}

// ---------------- K2: per-chunk class sums + A_d / X2_d partials -------------
// grid: 8 dim-groups (128 dims) x 32 row-chunks (128 rows) = 256 blocks, 128 thr
__global__ __launch_bounds__(128) void k_classpart(const float* __restrict__ X,
                                                   const int* __restrict__ tgt,
                                                   const int* __restrict__ counts,
                                                   float* __restrict__ csum_p,
                                                   float* __restrict__ a_p,
                                                   float* __restrict__ x2_p) {
    __shared__ float csum[NCLS * 128];
    __shared__ float cf[NCLS];
    __shared__ int   tch[128];
    int tid = threadIdx.x;
    int dg = blockIdx.x >> 5, ch = blockIdx.x & 31;
    int d = dg * 128 + tid;
    for (int c = 0; c < NCLS; c++) csum[c * 128 + tid] = 0.f;
    if (tid < NCLS) cf[tid] = (float)counts[tid];
    tch[tid] = tgt[ch * 128 + tid];
    __syncthreads();
    float a = 0.f, x2s = 0.f;
    const float* xp = X + (size_t)(ch * 128) * DIM + d;
    #pragma unroll 4
    for (int r = 0; r < 128; r++) {
        float x = xp[(size_t)r * DIM];
        int t = tch[r];
        csum[t * 128 + tid] += x;        // each thread owns its column: no race
        float xx = x * x;
        a += cf[t] * xx; x2s += xx;
    }
    for (int c = 0; c < NCLS; c++)
        csum_p[(size_t)(ch * NCLS + c) * DIM + d] = csum[c * 128 + tid];
    a_p[ch * DIM + d]  = a;
    x2_p[ch * DIM + d] = x2s;
}

// ---------------- K3a: reduce class-sum partials over chunks -----------------
__global__ __launch_bounds__(256) void k_csum_reduce(const float* __restrict__ csum_p,
                                                     float* __restrict__ classSum) {
    int idx = blockIdx.x * 256 + threadIdx.x;   // (c,d) flat, 65536
    float s = 0.f;
    #pragma unroll 8
    for (int ch = 0; ch < 32; ch++) s += csum_p[(size_t)ch * NCLS * DIM + idx];
    classSum[idx] = s;
}

// ---------------- K3b: weights_d ---------------------------------------------
__global__ __launch_bounds__(256) void k_weights(const float* __restrict__ classSum,
                                                 const float* __restrict__ a_p,
                                                 const float* __restrict__ x2_p,
                                                 const float* __restrict__ scal,
                                                 float* __restrict__ w) {
    int d = blockIdx.x * 256 + threadIdx.x;     // 0..1023
    float A = 0.f, X2 = 0.f;
    #pragma unroll 8
    for (int ch = 0; ch < 32; ch++) { A += a_p[ch * DIM + d]; X2 += x2_p[ch * DIM + d]; }
    float T = 0.f, SS = 0.f;
    #pragma unroll 8
    for (int c = 0; c < NCLS; c++) { float s = classSum[c * DIM + d]; T += s; SS += s * s; }
    float posnum = 2.f * (A - SS);
    float negnum = 2.f * ((float)N_ROWS * X2 - A - T * T + SS);
    w[d] = scal[1] / (negnum + EPSV) - scal[0] / (posnum + EPSV);
}

// ---------------- K4: xw, sq, bf16 casts -------------------------------------
__global__ __launch_bounds__(256) void k_prep(const float* __restrict__ X,
                                              const float* __restrict__ w,
                                              unsigned short* __restrict__ Xb,
                                              unsigned short* __restrict__ XWb,
                                              float* __restrict__ sq) {
    int row = blockIdx.x, tid = threadIdx.x;
    const float4* xr = (const float4*)(X + (size_t)row * DIM);
    const float4* wr = (const float4*)w;
    float4 x = xr[tid], ww = wr[tid];
    float4 xw = make_float4(x.x * ww.x, x.y * ww.y, x.z * ww.z, x.w * ww.w);
    float p = x.x * xw.x + x.y * xw.y + x.z * xw.z + x.w * xw.w;
    ushort4 xb, xwb;
    xb.x  = f2bf(x.x);  xb.y  = f2bf(x.y);  xb.z  = f2bf(x.z);  xb.w  = f2bf(x.w);
    xwb.x = f2bf(xw.x); xwb.y = f2bf(xw.y); xwb.z = f2bf(xw.z); xwb.w = f2bf(xw.w);
    ((ushort4*)(Xb  + (size_t)row * DIM))[tid] = xb;
    ((ushort4*)(XWb + (size_t)row * DIM))[tid] = xwb;
    for (int off = 32; off; off >>= 1) p += __shfl_down(p, off, 64);
    __shared__ float red[4];
    int wv = tid >> 6, ln = tid & 63;
    if (ln == 0) red[wv] = p;
    __syncthreads();
    if (tid == 0) sq[row] = red[0] + red[1] + red[2] + red[3];
}

// ---------------- K5: fused bf16 MFMA gram + softplus + masked mean ----------
// 528 upper-triangular 128x128 tiles; 256 thr = 4 waves, each wave 64x64 (4x4 MFMA frags)
__global__ __launch_bounds__(256) void k_gemm_loss(const unsigned short* __restrict__ Xb,
                                                   const unsigned short* __restrict__ XWb,
                                                   const float* __restrict__ sq,
                                                   const int* __restrict__ tgt,
                                                   float* __restrict__ loss) {
    __shared__ __align__(16) unsigned short As[128 * 32];
    __shared__ __align__(16) unsigned short Bs[128 * 32];
    __shared__ float sqI[128], sqJ[128];
    __shared__ int   tIs[128], tJs[128];
    __shared__ float red[4];

    int tid = threadIdx.x;
    int wave = tid >> 6, lane = tid & 63;

    // decode triangular (it, jt), jt >= it
    int b = blockIdx.x, it = 0, rl = 32;
    while (b >= rl) { b -= rl; rl--; it++; }
    int jt = it + b;

    // staging: 16 global_load_lds(16B) instrs per K-step, 4 per wave.
    // XOR-quad swizzle: logical quad q stored at physical quad p = q ^ ((row>>1)&3)
    const unsigned short* gp[4];
    unsigned short* lb[4];
    #pragma unroll
    for (int s = 0; s < 4; s++) {
        int gI = wave * 4 + s;              // 0..15 : <8 -> A tile, >=8 -> B tile
        int R  = gI * 16 + (lane >> 2);     // staging row 0..255
        int q  = (lane & 3) ^ ((R >> 1) & 3);
        int r  = R & 127;
        bool isA = R < 128;
        int grow = (isA ? it : jt) * 128 + r;
        const unsigned short* src = isA ? Xb : XWb;
        gp[s] = src + (size_t)grow * DIM + q * 8;
        lb[s] = (isA ? As : Bs) + (gI & 7) * (16 * 32);
    }

    // fragment LDS offsets (constant over k): A[m=lane&15][k=(lane>>4)*8+j]
    int lr = lane & 15, kq = lane >> 4;
    int offA[4], offB[4];
    int wrow = (wave >> 1) * 64, wcol = (wave & 1) * 64;
    #pragma unroll
    for (int mi = 0; mi < 4; mi++) {
        int row = wrow + mi * 16 + lr;
        offA[mi] = row * 32 + (kq ^ ((row >> 1) & 3)) * 8;
        int col = wcol + mi * 16 + lr;
        offB[mi] = col * 32 + (kq ^ ((col >> 1) & 3)) * 8;
    }

    f32x4 acc[4][4];
    #pragma unroll
    for (int i = 0; i < 4; i++)
        #pragma unroll
        for (int j = 0; j < 4; j++) acc[i][j] = (f32x4){0.f, 0.f, 0.f, 0.f};

    for (int kk = 0; kk < 32; kk++) {
        #pragma unroll
        for (int s = 0; s < 4; s++) async_cp16(gp[s] + kk * 32, lb[s]);
        __syncthreads();                    // drains vmcnt before barrier
        bf16x8 av[4], bv[4];
        #pragma unroll
        for (int i = 0; i < 4; i++) {
            av[i] = *(const bf16x8*)(As + offA[i]);
            bv[i] = *(const bf16x8*)(Bs + offB[i]);
        }
        #pragma unroll
        for (int i = 0; i < 4; i++)
            #pragma unroll
            for (int j = 0; j < 4; j++)
                acc[i][j] = __builtin_amdgcn_mfma_f32_16x16x32_bf16(av[i], bv[j], acc[i][j], 0, 0, 0);
        __syncthreads();
    }

    // epilogue: S = sq_i + sq_j - 2G, masked softplus, symmetric x2 off-diagonal
    if (tid < 128) { sqI[tid] = sq[it * 128 + tid]; tIs[tid] = tgt[it * 128 + tid]; }
    else { int u = tid - 128; sqJ[u] = sq[jt * 128 + u]; tJs[u] = tgt[jt * 128 + u]; }
    __syncthreads();

    float sum = 0.f;
    bool diagTile = (it == jt);
    #pragma unroll
    for (int j = 0; j < 4; j++) {
        int col = wcol + j * 16 + (lane & 15);            // C/D: col = lane&15
        float sj = sqJ[col]; int tj = tJs[col];
        #pragma unroll
        for (int i = 0; i < 4; i++) {
            int rbase = wrow + i * 16 + (lane >> 4) * 4;  // C/D: row = quad*4+reg
            #pragma unroll
            for (int r = 0; r < 4; r++) {
                int rowp = rbase + r;
                float S = sqI[rowp] + sj - 2.f * acc[i][j][r];
                float v;
                if (tIs[rowp] == tj) v = (diagTile && rowp == col) ? 0.f : softplus(-S);
                else                 v = softplus(S);
                sum += v;
            }
        }
    }
    float scale = (diagTile ? 1.f : 2.f) * (1.f / ((float)N_ROWS * (float)(N_ROWS - 1)));
    sum *= scale;
    for (int off = 32; off; off >>= 1) sum += __shfl_down(sum, off, 64);
    if (lane == 0) red[wave] = sum;
    __syncthreads();
    if (tid == 0) atomicAdd(loss, red[0] + red[1] + red[2] + red[3]);
}

extern "C" void kernel_launch(void* const* d_in, const int* in_sizes, int n_in,
                              void* d_out, int out_size, void* d_ws, size_t ws_size,
                              hipStream_t stream) {
    const float* X  = (const float*)d_in[0];
    const int* tgt  = (const int*)d_in[1];
    float* out = (float*)d_out;
    char* ws = (char*)d_ws;

    int*   counts   = (int*)ws;                                       // 256 B
    float* scal     = (float*)(ws + 256);                             // 2 floats
    float* w        = (float*)(ws + 512);                             // 4 KB
    float* sq       = (float*)(ws + 8192);                            // 16 KB
    unsigned short* Xb  = (unsigned short*)(ws + 32768);              // 8 MB
    unsigned short* XWb = (unsigned short*)(ws + 32768 + (8u << 20)); // 8 MB
    float* csum_p   = (float*)(ws + 32768 + (16u << 20));             // 8 MB
    float* classSum = (float*)(ws + 32768 + (24u << 20));             // 256 KB
    float* a_p      = (float*)(ws + 32768 + (24u << 20) + (256u << 10)); // 128 KB
    float* x2_p     = (float*)(ws + 32768 + (24u << 20) + (384u << 10)); // 128 KB

    k_counts     <<<1,    256, 0, stream>>>(tgt, counts, scal, out);
    k_classpart  <<<256,  128, 0, stream>>>(X, tgt, counts, csum_p, a_p, x2_p);
    k_csum_reduce<<<256,  256, 0, stream>>>(csum_p, classSum);
    k_weights    <<<4,    256, 0, stream>>>(classSum, a_p, x2_p, scal, w);
    k_prep       <<<4096, 256, 0, stream>>>(X, w, Xb, XWb, sq);
    k_gemm_loss  <<<528,  256, 0, stream>>>(Xb, XWb, sq, tgt, out);
}

// Round 2
// 135.117 us; speedup vs baseline: 1.1355x; 1.1355x over previous
//
#include <hip/hip_runtime.h>
#include <stdint.h>

#define N_ROWS 4096
#define DIM    1024
#define NCLS   64
#define EPSV   0.1f

typedef __attribute__((ext_vector_type(8))) __bf16 bf16x8;
typedef __attribute__((ext_vector_type(4))) float  f32x4;

__device__ __forceinline__ unsigned short f2bf(float f) {
    union { float f; unsigned u; } v; v.f = f;
    unsigned r = v.u + 0x7FFF + ((v.u >> 16) & 1);   // RNE
    return (unsigned short)(r >> 16);
}

__device__ __forceinline__ void async_cp16(const void* g, void* l) {
    __builtin_amdgcn_global_load_lds((const __attribute__((address_space(1))) void*)g,
                                     (__attribute__((address_space(3))) void*)l,
                                     16, 0, 0);
}

__device__ __forceinline__ float softplus(float x) {
    return fmaxf(x, 0.f) + __logf(1.f + __expf(-fabsf(x)));
}

// ---------------- K1: class counts + pair-count scalars + zero loss ----------
__global__ __launch_bounds__(256) void k_counts(const int* __restrict__ tgt,
                                                int* __restrict__ counts_out,
                                                float* __restrict__ scal,
                                                float* __restrict__ loss_out) {
    __shared__ int cnt[NCLS];
    int tid = threadIdx.x;
    if (tid < NCLS) cnt[tid] = 0;
    __syncthreads();
    for (int i = tid; i < N_ROWS; i += 256) atomicAdd(&cnt[tgt[i]], 1);
    __syncthreads();
    if (tid < NCLS) counts_out[tid] = cnt[tid];
    if (tid == 0) {
        long long sp = 0, ss = 0;
        for (int c = 0; c < NCLS; c++) { long long cc = cnt[c]; sp += cc * (cc - 1); ss += cc * cc; }
        scal[0] = (float)sp;                                       // cnt_pos
        scal[1] = (float)((long long)N_ROWS * N_ROWS - ss);        // cnt_neg
        loss_out[0] = 0.0f;
    }
}

// ---------------- K2: per-chunk class sums + A_d / X2_d partials -------------
__global__ __launch_bounds__(128) void k_classpart(const float* __restrict__ X,
                                                   const int* __restrict__ tgt,
                                                   const int* __restrict__ counts,
                                                   float* __restrict__ csum_p,
                                                   float* __restrict__ a_p,
                                                   float* __restrict__ x2_p) {
    __shared__ float csum[NCLS * 128];
    __shared__ float cf[NCLS];
    __shared__ int   tch[128];
    int tid = threadIdx.x;
    int dg = blockIdx.x >> 5, ch = blockIdx.x & 31;
    int d = dg * 128 + tid;
    for (int c = 0; c < NCLS; c++) csum[c * 128 + tid] = 0.f;
    if (tid < NCLS) cf[tid] = (float)counts[tid];
    tch[tid] = tgt[ch * 128 + tid];
    __syncthreads();
    float a = 0.f, x2s = 0.f;
    const float* xp = X + (size_t)(ch * 128) * DIM + d;
    #pragma unroll 4
    for (int r = 0; r < 128; r++) {
        float x = xp[(size_t)r * DIM];
        int t = tch[r];
        csum[t * 128 + tid] += x;        // each thread owns its column: no race
        float xx = x * x;
        a += cf[t] * xx; x2s += xx;
    }
    for (int c = 0; c < NCLS; c++)
        csum_p[(size_t)(ch * NCLS + c) * DIM + d] = csum[c * 128 + tid];
    a_p[ch * DIM + d]  = a;
    x2_p[ch * DIM + d] = x2s;
}

// ---------------- K3a: reduce class-sum partials over chunks -----------------
__global__ __launch_bounds__(256) void k_csum_reduce(const float* __restrict__ csum_p,
                                                     float* __restrict__ classSum) {
    int idx = blockIdx.x * 256 + threadIdx.x;   // (c,d) flat, 65536
    float s = 0.f;
    #pragma unroll 8
    for (int ch = 0; ch < 32; ch++) s += csum_p[(size_t)ch * NCLS * DIM + idx];
    classSum[idx] = s;
}

// ---------------- K3b: weights_d ---------------------------------------------
__global__ __launch_bounds__(256) void k_weights(const float* __restrict__ classSum,
                                                 const float* __restrict__ a_p,
                                                 const float* __restrict__ x2_p,
                                                 const float* __restrict__ scal,
                                                 float* __restrict__ w) {
    int d = blockIdx.x * 256 + threadIdx.x;     // 0..1023
    float A = 0.f, X2 = 0.f;
    #pragma unroll 8
    for (int ch = 0; ch < 32; ch++) { A += a_p[ch * DIM + d]; X2 += x2_p[ch * DIM + d]; }
    float T = 0.f, SS = 0.f;
    #pragma unroll 8
    for (int c = 0; c < NCLS; c++) { float s = classSum[c * DIM + d]; T += s; SS += s * s; }
    float posnum = 2.f * (A - SS);
    float negnum = 2.f * ((float)N_ROWS * X2 - A - T * T + SS);
    w[d] = scal[1] / (negnum + EPSV) - scal[0] / (posnum + EPSV);
}

// ---------------- K4: xw, sq, bf16 casts -------------------------------------
__global__ __launch_bounds__(256) void k_prep(const float* __restrict__ X,
                                              const float* __restrict__ w,
                                              unsigned short* __restrict__ Xb,
                                              unsigned short* __restrict__ XWb,
                                              float* __restrict__ sq) {
    int row = blockIdx.x, tid = threadIdx.x;
    const float4* xr = (const float4*)(X + (size_t)row * DIM);
    const float4* wr = (const float4*)w;
    float4 x = xr[tid], ww = wr[tid];
    float4 xw = make_float4(x.x * ww.x, x.y * ww.y, x.z * ww.z, x.w * ww.w);
    float p = x.x * xw.x + x.y * xw.y + x.z * xw.z + x.w * xw.w;
    ushort4 xb, xwb;
    xb.x  = f2bf(x.x);  xb.y  = f2bf(x.y);  xb.z  = f2bf(x.z);  xb.w  = f2bf(x.w);
    xwb.x = f2bf(xw.x); xwb.y = f2bf(xw.y); xwb.z = f2bf(xw.z); xwb.w = f2bf(xw.w);
    ((ushort4*)(Xb  + (size_t)row * DIM))[tid] = xb;
    ((ushort4*)(XWb + (size_t)row * DIM))[tid] = xwb;
    for (int off = 32; off; off >>= 1) p += __shfl_down(p, off, 64);
    __shared__ float red[4];
    int wv = tid >> 6, ln = tid & 63;
    if (ln == 0) red[wv] = p;
    __syncthreads();
    if (tid == 0) sq[row] = red[0] + red[1] + red[2] + red[3];
}

// ---------------- K5: fused bf16 MFMA gram + softplus + masked mean ----------
// 528 upper-triangular 128x128 tiles; 512 thr = 8 waves (2x4 wave grid, each
// wave 64x32 = 4x2 MFMA frags). Depth-1 double-buffered global_load_lds
// staging, single barrier per K-step.
__global__ __launch_bounds__(512) void k_gemm_loss(const unsigned short* __restrict__ Xb,
                                                   const unsigned short* __restrict__ XWb,
                                                   const float* __restrict__ sq,
                                                   const int* __restrict__ tgt,
                                                   float* __restrict__ loss) {
    __shared__ __align__(16) unsigned short As[2][128 * 32];
    __shared__ __align__(16) unsigned short Bs[2][128 * 32];
    __shared__ float sqI[128], sqJ[128];
    __shared__ int   tIs[128], tJs[128];
    __shared__ float red[8];

    int tid = threadIdx.x;
    int wave = tid >> 6, lane = tid & 63;

    // decode triangular (it, jt), jt >= it
    int b = blockIdx.x, it = 0, rl = 32;
    while (b >= rl) { b -= rl; rl--; it++; }
    int jt = it + b;

    // staging: 16 global_load_lds(16B) per K-step, 2 per wave.
    // XOR-quad swizzle: logical quad q stored at physical quad p = q ^ ((row>>1)&3)
    const unsigned short* gp[2];
    unsigned short* lb[2];
    #pragma unroll
    for (int s = 0; s < 2; s++) {
        int gI = wave * 2 + s;              // 0..15 : <8 -> A tile, >=8 -> B tile
        int R  = gI * 16 + (lane >> 2);     // staging row 0..255
        int q  = (lane & 3) ^ ((R >> 1) & 3);
        int r  = R & 127;
        bool isA = R < 128;
        int grow = (isA ? it : jt) * 128 + r;
        const unsigned short* src = isA ? Xb : XWb;
        gp[s] = src + (size_t)grow * DIM + q * 8;
        lb[s] = (isA ? &As[0][0] : &Bs[0][0]) + (gI & 7) * (16 * 32);
    }

    // fragment LDS offsets (constant over k): A[m=lane&15][k=(lane>>4)*8+j]
    int lr = lane & 15, kq = lane >> 4;
    int offA[4], offB[2];
    int wrow = (wave >> 2) * 64, wcol = (wave & 3) * 32;
    #pragma unroll
    for (int mi = 0; mi < 4; mi++) {
        int row = wrow + mi * 16 + lr;
        offA[mi] = row * 32 + (kq ^ ((row >> 1) & 3)) * 8;
    }
    #pragma unroll
    for (int nj = 0; nj < 2; nj++) {
        int col = wcol + nj * 16 + lr;
        offB[nj] = col * 32 + (kq ^ ((col >> 1) & 3)) * 8;
    }

    f32x4 acc[4][2];
    #pragma unroll
    for (int i = 0; i < 4; i++)
        #pragma unroll
        for (int j = 0; j < 2; j++) acc[i][j] = (f32x4){0.f, 0.f, 0.f, 0.f};

    // prologue: stage K-step 0 into buffer 0
    #pragma unroll
    for (int s = 0; s < 2; s++) async_cp16(gp[s], lb[s]);

    for (int kk = 0; kk < 32; kk++) {
        int buf = kk & 1;
        __syncthreads();                    // drains vmcnt: step-kk staging done,
                                            // prev compute's ds_reads done
        if (kk < 31) {                      // prefetch kk+1 into other buffer,
            #pragma unroll                  // overlaps with this step's MFMAs
            for (int s = 0; s < 2; s++) async_cp16(gp[s] + (kk + 1) * 32, lb[s] + (buf ^ 1) * (128 * 32));
        }
        const unsigned short* Ab = As[buf];
        const unsigned short* Bb = Bs[buf];
        bf16x8 av[4], bv[2];
        #pragma unroll
        for (int i = 0; i < 4; i++) av[i] = *(const bf16x8*)(Ab + offA[i]);
        #pragma unroll
        for (int j = 0; j < 2; j++) bv[j] = *(const bf16x8*)(Bb + offB[j]);
        #pragma unroll
        for (int i = 0; i < 4; i++)
            #pragma unroll
            for (int j = 0; j < 2; j++)
                acc[i][j] = __builtin_amdgcn_mfma_f32_16x16x32_bf16(av[i], bv[j], acc[i][j], 0, 0, 0);
    }

    // epilogue: S = sq_i + sq_j - 2G, masked softplus, symmetric x2 off-diagonal
    if (tid < 128)      { sqI[tid] = sq[it * 128 + tid]; tIs[tid] = tgt[it * 128 + tid]; }
    else if (tid < 256) { int u = tid - 128; sqJ[u] = sq[jt * 128 + u]; tJs[u] = tgt[jt * 128 + u]; }
    __syncthreads();

    float sum = 0.f;
    bool diagTile = (it == jt);
    #pragma unroll
    for (int j = 0; j < 2; j++) {
        int col = wcol + j * 16 + (lane & 15);            // C/D: col = lane&15
        float sj = sqJ[col]; int tj = tJs[col];
        #pragma unroll
        for (int i = 0; i < 4; i++) {
            int rbase = wrow + i * 16 + (lane >> 4) * 4;  // C/D: row = quad*4+reg
            #pragma unroll
            for (int r = 0; r < 4; r++) {
                int rowp = rbase + r;
                float S = sqI[rowp] + sj - 2.f * acc[i][j][r];
                float v;
                if (tIs[rowp] == tj) v = (diagTile && rowp == col) ? 0.f : softplus(-S);
                else                 v = softplus(S);
                sum += v;
            }
        }
    }
    float scale = (diagTile ? 1.f : 2.f) * (1.f / ((float)N_ROWS * (float)(N_ROWS - 1)));
    sum *= scale;
    for (int off = 32; off; off >>= 1) sum += __shfl_down(sum, off, 64);
    if (lane == 0) red[wave] = sum;
    __syncthreads();
    if (tid == 0) {
        float t = 0.f;
        #pragma unroll
        for (int wv = 0; wv < 8; wv++) t += red[wv];
        atomicAdd(loss, t);
    }
}

extern "C" void kernel_launch(void* const* d_in, const int* in_sizes, int n_in,
                              void* d_out, int out_size, void* d_ws, size_t ws_size,
                              hipStream_t stream) {
    const float* X  = (const float*)d_in[0];
    const int* tgt  = (const int*)d_in[1];
    float* out = (float*)d_out;
    char* ws = (char*)d_ws;

    int*   counts   = (int*)ws;                                       // 256 B
    float* scal     = (float*)(ws + 256);                             // 2 floats
    float* w        = (float*)(ws + 512);                             // 4 KB
    float* sq       = (float*)(ws + 8192);                            // 16 KB
    unsigned short* Xb  = (unsigned short*)(ws + 32768);              // 8 MB
    unsigned short* XWb = (unsigned short*)(ws + 32768 + (8u << 20)); // 8 MB
    float* csum_p   = (float*)(ws + 32768 + (16u << 20));             // 8 MB
    float* classSum = (float*)(ws + 32768 + (24u << 20));             // 256 KB
    float* a_p      = (float*)(ws + 32768 + (24u << 20) + (256u << 10)); // 128 KB
    float* x2_p     = (float*)(ws + 32768 + (24u << 20) + (384u << 10)); // 128 KB

    k_counts     <<<1,    256, 0, stream>>>(tgt, counts, scal, out);
    k_classpart  <<<256,  128, 0, stream>>>(X, tgt, counts, csum_p, a_p, x2_p);
    k_csum_reduce<<<256,  256, 0, stream>>>(csum_p, classSum);
    k_weights    <<<4,    256, 0, stream>>>(classSum, a_p, x2_p, scal, w);
    k_prep       <<<4096, 256, 0, stream>>>(X, w, Xb, XWb, sq);
    k_gemm_loss  <<<528,  512, 0, stream>>>(Xb, XWb, sq, tgt, out);
}